// Round 6
// baseline (251.209 us; speedup 1.0000x reference)
//
#include <hip/hip_runtime.h>
#include <hip/hip_fp16.h>
#include <hip/hip_cooperative_groups.h>

namespace cg = cooperative_groups;

#define N_NODES 100000
#define N_EDGES 3200000
#define IN_DIM  62
#define OUT_DIM 16

#define EBC    4096                                   // edges per append unit
#define EPT    4                                      // edges per thread
#define NEB    ((N_EDGES + EBC - 1) / EBC)            // 782 append/count units
#define NPB    ((N_NODES + 1023) / 1024)              // 98 proj units
#define NBUCK  ((N_NODES + 63) / 64)                  // 1563 buckets (dst>>6)
#define CAPL   4096                                   // gather LDS capacity
#define NCU    256

typedef int nat_i2 __attribute__((ext_vector_type(2)));   // builtin-legal int2

// ---------------- shared-memory arenas (union: phases are exclusive) ------
struct AppendSh {                                // ~58.4 KB (also used by count)
    int  cnt[NBUCK];
    int  pfx[NBUCK];
    int  combo[NBUCK];
    int2 pay[EBC];
    unsigned short pbkt[EBC];
    int  wsum[16];
};
struct GatherSh {                                // ~57.0 KB
    int2 rec[CAPL];                              // .x becomes w bits
    unsigned short inv[CAPL];
    unsigned int exb[CAPL];                      // packed half2(ex0,ex1)
    int hist[64], pfx[64], cur[64];
    float adst_l[64];
};
union ShArena { AppendSh a; GatherSh g; };

// ---------------- unit: node projection (no LDS) --------------------------
__device__ __forceinline__ void do_proj(
    int u, int tid,
    const float* __restrict__ h, const float* __restrict__ W_fc,
    const float* __restrict__ W_attn,
    __half* __restrict__ zh, float* __restrict__ a_src_arr,
    float* __restrict__ a_dst_arr)
{
    int i = u * 1024 + tid;
    if (i >= N_NODES) return;                    // block-local; no barriers inside

    float acc[OUT_DIM];
#pragma unroll
    for (int j = 0; j < OUT_DIM; ++j) acc[j] = 0.f;

    const float2* __restrict__ hr = (const float2*)(h + (size_t)i * IN_DIM);
#pragma unroll
    for (int kk = 0; kk < IN_DIM / 2; ++kk) {
        float2 hv = hr[kk];
#pragma unroll
        for (int j = 0; j < OUT_DIM; ++j) {
            acc[j] += hv.x * W_fc[j * IN_DIM + 2 * kk]
                    + hv.y * W_fc[j * IN_DIM + 2 * kk + 1];
        }
    }

    float asrc = 0.f, adst = 0.f;
#pragma unroll
    for (int j = 0; j < OUT_DIM; ++j) {
        asrc += acc[j] * W_attn[j];
        adst += acc[j] * W_attn[OUT_DIM + j];
    }

    union { __half hx[16]; uint4 q[2]; } uq;
#pragma unroll
    for (int j = 0; j < OUT_DIM; ++j) uq.hx[j] = __float2half(acc[j]);
    uint4* __restrict__ zrow = (uint4*)(zh + (size_t)i * OUT_DIM);
    zrow[0] = uq.q[0];
    zrow[1] = uq.q[1];

    a_src_arr[i] = asrc;
    a_dst_arr[i] = adst;
}

// ---------------- unit: count one EBC edge chunk ---------------------------
// LDS histogram -> PLAIN coalesced store of the block-major counts column.
// Zero global atomics.
__device__ __forceinline__ void do_count(
    int be, int tid, AppendSh& S,
    const int* __restrict__ dst, int* __restrict__ counts)
{
    __syncthreads();                             // arena reuse guard
    for (int t = tid; t < NBUCK; t += 1024) S.cnt[t] = 0;
    __syncthreads();

    long ebase = (long)be * EBC;
    int chunk_n = (int)min((long)EBC, (long)N_EDGES - ebase);
    for (int p = tid; p < chunk_n; p += 1024)
        atomicAdd(&S.cnt[dst[ebase + p] >> 6], 1);   // LDS int atomic (fast path)
    __syncthreads();

    int* col = counts + (size_t)be * NBUCK;      // block-major: coalesced store
    for (int t = tid; t < NBUCK; t += 1024) col[t] = S.cnt[t];
}

// ---------------- unit: scan one bucket across all blocks -----------------
// One wave per bucket: exclusive prefix over the 782 per-block counts.
// Reads block-major counts (scattered, L2-resident), writes bucket-major
// bases (coalesced) + totals[b]. Zero atomics.
__device__ __forceinline__ void do_scan_bucket(
    int b, int lane, const int* __restrict__ counts,
    int* __restrict__ bases, int* __restrict__ totals)
{
    int run = 0;
#pragma unroll
    for (int k = 0; k < (NEB + 63) / 64; ++k) {  // 13 chunks
        int be = k * 64 + lane;
        int c = (be < NEB) ? counts[(size_t)be * NBUCK + b] : 0;
        int x = c;
#pragma unroll
        for (int off = 1; off < 64; off <<= 1) {
            int y = __shfl_up(x, off, 64);
            if (lane >= off) x += y;
        }
        if (be < NEB) bases[(size_t)b * NEB + be] = run + x - c;  // exclusive
        run += __shfl(x, 63, 64);
    }
    if (lane == 0) totals[b] = run;
}

// ---------------- unit: bucket-append one EBC edge chunk -------------------
// Round-2 proven structure, with the cursor atomic-with-return replaced by
// a plain load of the precomputed base. Zero global atomics.
__device__ __forceinline__ void do_append(
    int be, int tid, AppendSh& S,
    const float* __restrict__ e, const int* __restrict__ src,
    const int* __restrict__ dst, const int* __restrict__ bases,
    nat_i2* __restrict__ records, int cap)
{
    __syncthreads();                             // arena reuse guard

    long ebase = (long)be * EBC;
    int chunk_n = (int)min((long)EBC, (long)N_EDGES - ebase);

    int dv[EPT], sv[EPT];
    float2 ev[EPT];
#pragma unroll
    for (int j = 0; j < EPT; ++j) {
        int p = tid + j * 1024;
        dv[j] = -1;
        if (p < chunk_n) {
            long eid = ebase + p;
            dv[j] = dst[eid];
            sv[j] = src[eid];
            ev[j] = ((const float2*)e)[eid];
        }
    }

    for (int t = tid; t < NBUCK; t += 1024) S.cnt[t] = 0;
    __syncthreads();

#pragma unroll
    for (int j = 0; j < EPT; ++j)
        if (dv[j] >= 0) atomicAdd(&S.cnt[dv[j] >> 6], 1);
    __syncthreads();

    // own bucket pair: read count, zero rank counter, load PRECOMPUTED base
    int b0 = 2 * tid, b1 = b0 + 1;
    int c0 = (b0 < NBUCK) ? S.cnt[b0] : 0;
    int c1 = (b1 < NBUCK) ? S.cnt[b1] : 0;
    if (b0 < NBUCK) S.cnt[b0] = 0;
    if (b1 < NBUCK) S.cnt[b1] = 0;
    int gb0 = 0, gb1 = 0;
    if (b0 < NBUCK) gb0 = bases[(size_t)b0 * NEB + be];   // plain L2 load
    if (b1 < NBUCK) gb1 = bases[(size_t)b1 * NEB + be];

    // block-wide exclusive scan via wave shuffles (hides the base loads)
    int ts = c0 + c1;
    {
        int lane = tid & 63, wid = tid >> 6;
        int x = ts;
#pragma unroll
        for (int off = 1; off < 64; off <<= 1) {
            int y = __shfl_up(x, off, 64);
            if (lane >= off) x += y;
        }
        if (lane == 63) S.wsum[wid] = x;
        __syncthreads();
        if (wid == 0) {
            int v = (lane < 16) ? S.wsum[lane] : 0;
#pragma unroll
            for (int off = 1; off < 16; off <<= 1) {
                int y = __shfl_up(v, off, 64);
                if (lane >= off) v += y;
            }
            if (lane < 16) S.wsum[lane] = v;
        }
        __syncthreads();
        int texcl = x - ts + (wid ? S.wsum[wid - 1] : 0);
        if (b0 < NBUCK) { S.pfx[b0] = texcl;      S.combo[b0] = b0 * cap + gb0 - texcl; }
        if (b1 < NBUCK) { S.pfx[b1] = texcl + c0; S.combo[b1] = b1 * cap + gb1 - (texcl + c0); }
    }
    __syncthreads();

    // B1: payload (in regs) -> sorted LDS slot
#pragma unroll
    for (int j = 0; j < EPT; ++j) {
        if (dv[j] >= 0) {
            int b = dv[j] >> 6;
            union { __half2 h2; int i; } uu;
            uu.h2.x = __float2half(ev[j].x);
            uu.h2.y = __float2half(ev[j].y);
            int r = atomicAdd(&S.cnt[b], 1);
            int q = S.pfx[b] + r;
            S.pay[q]  = make_int2(uu.i, sv[j] | ((dv[j] & 63) << 17));
            S.pbkt[q] = (unsigned short)b;
        }
    }
    __syncthreads();

    // B2: LDS -> global, sorted order (merged-line nt stores)
    for (int p = tid; p < chunk_n; p += 1024) {
        int2 v  = S.pay[p];
        int  bb = S.pbkt[p];
        int pos = S.combo[bb] + p;
        if (pos < (bb + 1) * cap) {              // overflow: >22 sigma
            nat_i2 vv; vv.x = v.x; vv.y = v.y;
            __builtin_nontemporal_store(vv, records + pos);
        }
    }
}

// ---------------- unit: gather one 64-node bucket --------------------------
// Round-2 proven structure verbatim (int LDS atomics only).
__device__ __forceinline__ void do_gather(
    int b, int tid, GatherSh& S,
    const int* __restrict__ totals, const nat_i2* __restrict__ records,
    const __half* __restrict__ zh, const float* __restrict__ a_src_arr,
    const float* __restrict__ a_dst_arr, const float* __restrict__ W_attn,
    const float* __restrict__ W_edge, const float* __restrict__ W_e2n,
    float* __restrict__ out, int cap)
{
    __syncthreads();                             // arena reuse guard

    long lo = (long)b * cap;
    int n   = totals[b];
    int nl  = n < cap ? n : cap;                 // cap <= CAPL always

    if (tid < 64) {
        S.hist[tid] = 0; S.cur[tid] = 0;
        int node = (b << 6) + tid;
        S.adst_l[tid] = (node < N_NODES) ? a_dst_arr[node] : 0.f;
    }
    __syncthreads();

    float we00 = W_edge[0], we01 = W_edge[1], we10 = W_edge[2], we11 = W_edge[3];
    float wa0  = W_attn[2 * OUT_DIM], wa1 = W_attn[2 * OUT_DIM + 1];

    int ld0 = -1, ld1 = -1, ld2 = -1, ld3 = -1;
#define EDGEW(J, LD)                                                        \
    {                                                                       \
        int k = tid + (J) * 1024;                                           \
        if (k < nl) {                                                       \
            nat_i2 r = __builtin_nontemporal_load(records + lo + k);        \
            int s  = r.y & 0x1FFFF;                                         \
            LD     = (r.y >> 17) & 63;                                      \
            union { int i; __half2 h2; } ue; ue.i = r.x;                    \
            float e0 = __low2float(ue.h2), e1 = __high2float(ue.h2);        \
            float ex0 = e0 * we00 + e1 * we01;                              \
            float ex1 = e0 * we10 + e1 * we11;                              \
            float a = a_src_arr[s] + S.adst_l[LD] + ex0 * wa0 + ex1 * wa1;  \
            float ea = (a > 0.f) ? a : 0.01f * a;                           \
            float w  = __expf(ea);                                          \
            S.rec[k] = make_int2(__float_as_int(w), r.y);                   \
            union { unsigned int i; __half2 h2; } up;                       \
            up.h2.x = __float2half(ex0);                                    \
            up.h2.y = __float2half(ex1);                                    \
            S.exb[k] = up.i;                                                \
            atomicAdd(&S.hist[LD], 1);                                      \
        }                                                                   \
    }
    EDGEW(0, ld0) EDGEW(1, ld1) EDGEW(2, ld2) EDGEW(3, ld3)
#undef EDGEW
    __syncthreads();

    // exclusive scan of 64 per-node counts
    if (tid < 64) S.pfx[tid] = S.hist[tid];
    __syncthreads();
    for (int off = 1; off < 64; off <<= 1) {
        int t = 0;
        if (tid < 64 && tid >= off) t = S.pfx[tid - off];
        __syncthreads();
        if (tid < 64) S.pfx[tid] += t;
        __syncthreads();
    }
    if (tid < 64) S.pfx[tid] -= S.hist[tid];     // exclusive
    __syncthreads();

    // inverse permutation (ld cached in regs from phase A)
#define INVW(J, LD)                                                         \
    if (LD >= 0) {                                                          \
        int k = tid + (J) * 1024;                                           \
        int r = atomicAdd(&S.cur[LD], 1);                                   \
        S.inv[S.pfx[LD] + r] = (unsigned short)k;                           \
    }
    INVW(0, ld0) INVW(1, ld1) INVW(2, ld2) INVW(3, ld3)
#undef INVW
    __syncthreads();

    // phase B: group = node, 16 lanes = features
    int ld   = tid >> 4;
    int lane = tid & 15;
    int node = (b << 6) + ld;

    int m    = S.hist[ld];
    int base = S.pfx[ld];

    float acc0 = 0.f, acc1 = 0.f, accw0 = 0.f, accw1 = 0.f;
    float ax00 = 0.f, ax01 = 0.f, ax10 = 0.f, ax11 = 0.f;

    int i = 0;
    for (; i + 1 < m; i += 2) {
        int k0 = S.inv[base + i];
        int k1 = S.inv[base + i + 1];
        int2 r0 = S.rec[k0];
        int2 r1 = S.rec[k1];
        float w0 = __int_as_float(r0.x);
        float w1 = __int_as_float(r1.x);
        int s0 = r0.y & 0x1FFFF;
        int s1 = r1.y & 0x1FFFF;
        union { unsigned int i; __half2 h2; } x0, x1;
        x0.i = S.exb[k0];
        x1.i = S.exb[k1];

        float zv0 = __half2float(zh[s0 * OUT_DIM + lane]);
        float zv1 = __half2float(zh[s1 * OUT_DIM + lane]);

        acc0  += w0 * zv0;                 acc1  += w1 * zv1;
        accw0 += w0;                       accw1 += w1;
        ax00  += w0 * __low2float(x0.h2);  ax01  += w1 * __low2float(x1.h2);
        ax10  += w0 * __high2float(x0.h2); ax11  += w1 * __high2float(x1.h2);
    }
    if (i < m) {
        int k0 = S.inv[base + i];
        int2 r0 = S.rec[k0];
        float w0 = __int_as_float(r0.x);
        int s0 = r0.y & 0x1FFFF;
        union { unsigned int i; __half2 h2; } x0;
        x0.i = S.exb[k0];
        float zv0 = __half2float(zh[s0 * OUT_DIM + lane]);
        acc0  += w0 * zv0;
        accw0 += w0;
        ax00  += w0 * __low2float(x0.h2);
        ax10  += w0 * __high2float(x0.h2);
    }

    if (node < N_NODES) {
        float acc  = acc0 + acc1;
        float accw = accw0 + accw1;
        float ax0  = ax00 + ax01;
        float ax1  = ax10 + ax11;

        float ez   = ax0 * W_e2n[2 * lane] + ax1 * W_e2n[2 * lane + 1];
        float invw = (accw != 0.f) ? (1.f / accw) : 0.f;
        out[(size_t)node * OUT_DIM + lane] = (acc + ez) * invw;
    }
}

// ============ fused cooperative persistent kernel ==========================
// ONE dispatch, FOUR phases, ZERO global atomics:
//   P1 proj + count -> P2 per-bucket scan -> P3 deterministic append -> P4 gather
__global__ __launch_bounds__(1024) void fused_kernel(
    const float* __restrict__ h, const float* __restrict__ e,
    const int* __restrict__ src, const int* __restrict__ dst,
    const float* __restrict__ W_fc, const float* __restrict__ W_attn,
    const float* __restrict__ W_edge, const float* __restrict__ W_e2n,
    __half* __restrict__ zh, float* __restrict__ a_src_arr,
    float* __restrict__ a_dst_arr, int* __restrict__ counts,
    int* __restrict__ bases, int* __restrict__ totals,
    nat_i2* __restrict__ records, float* __restrict__ out, int cap)
{
    __shared__ ShArena sh;
    cg::grid_group grid = cg::this_grid();
    int tid = threadIdx.x;

    // P1: proj units + count units (no ordering dependency between them)
    for (int u = blockIdx.x; u < NPB + NEB; u += gridDim.x) {
        if (u < NPB) do_proj(u, tid, h, W_fc, W_attn, zh, a_src_arr, a_dst_arr);
        else         do_count(u - NPB, tid, sh.a, dst, counts);
    }
    grid.sync();

    // P2: one wave per bucket scans per-block counts into bases/totals
    {
        int lane = tid & 63;
        int gw   = blockIdx.x * (1024 / 64) + (tid >> 6);
        for (int b = gw; b < NBUCK; b += gridDim.x * (1024 / 64))
            do_scan_bucket(b, lane, counts, bases, totals);
    }
    grid.sync();

    // P3: append units with precomputed bases
    for (int u = blockIdx.x; u < NEB; u += gridDim.x)
        do_append(u, tid, sh.a, e, src, dst, bases, records, cap);
    grid.sync();

    // P4: gather units
    for (int b = blockIdx.x; b < NBUCK; b += gridDim.x)
        do_gather(b, tid, sh.g, totals, records, zh, a_src_arr, a_dst_arr,
                  W_attn, W_edge, W_e2n, out, cap);
}

// ============ fallback: same pipeline, 4 plain dispatches ==================
__global__ __launch_bounds__(1024) void proj_count_kernel(
    const float* __restrict__ h, const float* __restrict__ W_fc,
    const float* __restrict__ W_attn, const int* __restrict__ dst,
    __half* __restrict__ zh, float* __restrict__ a_src_arr,
    float* __restrict__ a_dst_arr, int* __restrict__ counts)
{
    __shared__ AppendSh sh;
    if (blockIdx.x < NPB)
        do_proj(blockIdx.x, threadIdx.x, h, W_fc, W_attn, zh, a_src_arr, a_dst_arr);
    else
        do_count(blockIdx.x - NPB, threadIdx.x, sh, dst, counts);
}

__global__ __launch_bounds__(256) void scan_kernel(
    const int* __restrict__ counts, int* __restrict__ bases,
    int* __restrict__ totals)
{
    int lane = threadIdx.x & 63;
    int gw   = blockIdx.x * 4 + (threadIdx.x >> 6);
    if (gw < NBUCK) do_scan_bucket(gw, lane, counts, bases, totals);
}

__global__ __launch_bounds__(1024) void append_kernel(
    const float* __restrict__ e, const int* __restrict__ src,
    const int* __restrict__ dst, const int* __restrict__ bases,
    nat_i2* __restrict__ records, int cap)
{
    __shared__ AppendSh sh;
    do_append(blockIdx.x, threadIdx.x, sh, e, src, dst, bases, records, cap);
}

__global__ __launch_bounds__(1024) void gather_kernel(
    const int* __restrict__ totals, const nat_i2* __restrict__ records,
    const __half* __restrict__ zh, const float* __restrict__ a_src_arr,
    const float* __restrict__ a_dst_arr, const float* __restrict__ W_attn,
    const float* __restrict__ W_edge, const float* __restrict__ W_e2n,
    float* __restrict__ out, int cap)
{
    __shared__ GatherSh sh;
    do_gather(blockIdx.x, threadIdx.x, sh, totals, records, zh,
              a_src_arr, a_dst_arr, W_attn, W_edge, W_e2n, out, cap);
}

// ================= last-resort atomic path (round-1, known-passing) =======

__global__ __launch_bounds__(256) void node_proj_fb_kernel(
    const float* __restrict__ h,
    const float* __restrict__ W_fc,
    const float* __restrict__ W_attn,
    float* __restrict__ z,
    float* __restrict__ a_src_arr,
    float* __restrict__ a_dst_arr,
    float* __restrict__ denom,
    float* __restrict__ out)
{
    int i = blockIdx.x * blockDim.x + threadIdx.x;
    if (i >= N_NODES) return;

    float acc[OUT_DIM];
#pragma unroll
    for (int j = 0; j < OUT_DIM; ++j) acc[j] = 0.f;

    const float2* __restrict__ hr = (const float2*)(h + (size_t)i * IN_DIM);
#pragma unroll
    for (int kk = 0; kk < IN_DIM / 2; ++kk) {
        float2 hv = hr[kk];
#pragma unroll
        for (int j = 0; j < OUT_DIM; ++j) {
            acc[j] += hv.x * W_fc[j * IN_DIM + 2 * kk]
                    + hv.y * W_fc[j * IN_DIM + 2 * kk + 1];
        }
    }

    float asrc = 0.f, adst = 0.f;
#pragma unroll
    for (int j = 0; j < OUT_DIM; ++j) {
        asrc += acc[j] * W_attn[j];
        adst += acc[j] * W_attn[OUT_DIM + j];
    }

    float4* __restrict__ zrow = (float4*)(z + (size_t)i * OUT_DIM);
    zrow[0] = make_float4(acc[0],  acc[1],  acc[2],  acc[3]);
    zrow[1] = make_float4(acc[4],  acc[5],  acc[6],  acc[7]);
    zrow[2] = make_float4(acc[8],  acc[9],  acc[10], acc[11]);
    zrow[3] = make_float4(acc[12], acc[13], acc[14], acc[15]);

    a_src_arr[i] = asrc;
    a_dst_arr[i] = adst;
    denom[i] = 0.f;

    float4 z4 = make_float4(0.f, 0.f, 0.f, 0.f);
    float4* __restrict__ orow = (float4*)(out + (size_t)i * OUT_DIM);
    orow[0] = z4; orow[1] = z4; orow[2] = z4; orow[3] = z4;
}

__global__ __launch_bounds__(256) void edge_kernel(
    const float* __restrict__ e,
    const int*   __restrict__ src,
    const int*   __restrict__ dst,
    const float* __restrict__ W_attn,
    const float* __restrict__ W_edge,
    const float* __restrict__ W_e2n,
    const float* __restrict__ z,
    const float* __restrict__ a_src_arr,
    const float* __restrict__ a_dst_arr,
    float* __restrict__ denom,
    float* __restrict__ out)
{
    int eid = blockIdx.x * blockDim.x + threadIdx.x;
    if (eid >= N_EDGES) return;

    int s = src[eid];
    int d = dst[eid];

    float2 ev = ((const float2*)e)[eid];
    float ex0 = ev.x * W_edge[0] + ev.y * W_edge[1];
    float ex1 = ev.x * W_edge[2] + ev.y * W_edge[3];

    float a = a_src_arr[s] + a_dst_arr[d]
            + ex0 * W_attn[2 * OUT_DIM] + ex1 * W_attn[2 * OUT_DIM + 1];
    float ea = (a > 0.f) ? a : 0.01f * a;
    float w  = __expf(ea);

    unsafeAtomicAdd(denom + d, w);

    const float4* __restrict__ zrow = (const float4*)(z + (size_t)s * OUT_DIM);
    float4 z0 = zrow[0], z1 = zrow[1], z2 = zrow[2], z3 = zrow[3];

    float* __restrict__ orow = out + (size_t)d * OUT_DIM;
    float zs[OUT_DIM] = { z0.x, z0.y, z0.z, z0.w,
                          z1.x, z1.y, z1.z, z1.w,
                          z2.x, z2.y, z2.z, z2.w,
                          z3.x, z3.y, z3.z, z3.w };
#pragma unroll
    for (int j = 0; j < OUT_DIM; ++j) {
        float ez = ex0 * W_e2n[2 * j] + ex1 * W_e2n[2 * j + 1];
        unsafeAtomicAdd(orow + j, w * (zs[j] + ez));
    }
}

__global__ __launch_bounds__(256) void normalize_kernel(
    float* __restrict__ out, const float* __restrict__ denom)
{
    int tid = blockIdx.x * blockDim.x + threadIdx.x;
    const int total = N_NODES * OUT_DIM / 4;
    if (tid >= total) return;
    int n = tid >> 2;
    float dn = denom[n];
    float inv = (dn != 0.f) ? (1.f / dn) : 0.f;
    float4 v = ((float4*)out)[tid];
    v.x *= inv; v.y *= inv; v.z *= inv; v.w *= inv;
    ((float4*)out)[tid] = v;
}

extern "C" void kernel_launch(void* const* d_in, const int* in_sizes, int n_in,
                              void* d_out, int out_size, void* d_ws, size_t ws_size,
                              hipStream_t stream)
{
    const float* h      = (const float*)d_in[0];
    const float* e      = (const float*)d_in[1];
    const int*   src    = (const int*)  d_in[2];
    const int*   dst    = (const int*)  d_in[3];
    const float* W_fc   = (const float*)d_in[4];
    const float* W_attn = (const float*)d_in[5];
    const float* W_edge = (const float*)d_in[6];
    const float* W_e2n  = (const float*)d_in[7];
    float* out = (float*)d_out;

    char* ws = (char*)d_ws;

    // ---- layout: zh | a_src | a_dst | totals | counts | bases | records ----
    size_t off = 0;
    __half* zh        = (__half*)(ws + off); off += (size_t)N_NODES * OUT_DIM * 2;
    float*  a_src_arr = (float*) (ws + off); off += (size_t)N_NODES * 4;
    float*  a_dst_arr = (float*) (ws + off); off += (size_t)N_NODES * 4;
    off = (off + 255) & ~(size_t)255;
    int* totals = (int*)(ws + off); off += ((size_t)NBUCK * 4 + 255) & ~(size_t)255;
    int* counts = (int*)(ws + off); off += ((size_t)NEB * NBUCK * 4 + 255) & ~(size_t)255;
    int* bases  = (int*)(ws + off); off += ((size_t)NBUCK * NEB * 4 + 255) & ~(size_t)255;
    size_t rec_off = (off + 255) & ~(size_t)255;

    // per-bucket capacity tiers: mean load 2048, sigma ~45
    int cap = 0;
    if      (ws_size >= rec_off + (size_t)NBUCK * 4096 * 8) cap = 4096;
    else if (ws_size >= rec_off + (size_t)NBUCK * 3072 * 8) cap = 3072;
    else if (ws_size >= rec_off + (size_t)NBUCK * 2560 * 8) cap = 2560;
    else if (ws_size >= rec_off + (size_t)NBUCK * 2304 * 8) cap = 2304;

    if (cap) {
        nat_i2* records = (nat_i2*)(ws + rec_off);

        // ---- preferred: single cooperative persistent dispatch ----
        hipError_t lerr = hipErrorUnknown;
        int maxB = 0;
        hipError_t qerr = hipOccupancyMaxActiveBlocksPerMultiprocessor(
            &maxB, reinterpret_cast<const void*>(fused_kernel), 1024, 0);
        if (qerr == hipSuccess && maxB > 0) {
            int gridB = (maxB >= 2 ? 2 : 1) * NCU;
            void* kargs[] = {
                (void*)&h, (void*)&e, (void*)&src, (void*)&dst,
                (void*)&W_fc, (void*)&W_attn, (void*)&W_edge, (void*)&W_e2n,
                (void*)&zh, (void*)&a_src_arr, (void*)&a_dst_arr,
                (void*)&counts, (void*)&bases, (void*)&totals,
                (void*)&records, (void*)&out, (void*)&cap };
            lerr = hipLaunchCooperativeKernel(
                reinterpret_cast<const void*>(fused_kernel),
                dim3(gridB), dim3(1024), kargs, 0, stream);
        }

        if (lerr != hipSuccess) {
            // ---- same pipeline, 4 plain dispatches (no atomics either) ----
            proj_count_kernel<<<NPB + NEB, 1024, 0, stream>>>(
                h, W_fc, W_attn, dst, zh, a_src_arr, a_dst_arr, counts);

            scan_kernel<<<(NBUCK + 3) / 4, 256, 0, stream>>>(
                counts, bases, totals);

            append_kernel<<<NEB, 1024, 0, stream>>>(
                e, src, dst, bases, records, cap);

            gather_kernel<<<NBUCK, 1024, 0, stream>>>(
                totals, records, zh, a_src_arr, a_dst_arr,
                W_attn, W_edge, W_e2n, out, cap);
        }
    } else {
        // -------- round-1 atomic fallback (needs ~8 MB) --------
        size_t foff = 0;
        float* z     = (float*)(ws + foff); foff += (size_t)N_NODES * OUT_DIM * 4;
        float* asrc  = (float*)(ws + foff); foff += (size_t)N_NODES * 4;
        float* adst  = (float*)(ws + foff); foff += (size_t)N_NODES * 4;
        float* denom = (float*)(ws + foff); foff += (size_t)N_NODES * 4;

        node_proj_fb_kernel<<<(N_NODES + 255) / 256, 256, 0, stream>>>(
            h, W_fc, W_attn, z, asrc, adst, denom, out);

        edge_kernel<<<(N_EDGES + 255) / 256, 256, 0, stream>>>(
            e, src, dst, W_attn, W_edge, W_e2n, z, asrc, adst, denom, out);

        normalize_kernel<<<(N_NODES * OUT_DIM / 4 + 255) / 256, 256, 0, stream>>>(
            out, denom);
    }
}

// Round 7
// 219.571 us; speedup vs baseline: 1.1441x; 1.1441x over previous
//
#include <hip/hip_runtime.h>
#include <hip/hip_fp16.h>

#define N_NODES 100000
#define N_EDGES 3200000
#define IN_DIM  62
#define OUT_DIM 16

#define EBC    6144                                   // edges per append block
#define EPT    (EBC / 1024)                           // 6 edges per thread
#define NEB    ((N_EDGES + EBC - 1) / EBC)            // 521 append blocks
#define NPB    ((N_NODES + 1023) / 1024)              // 98 proj blocks (1024 thr)
#define NBUCK  ((N_NODES + 63) / 64)                  // 1563 buckets (dst>>6)
#define CSTR   16                                     // cursor stride (ints) = 64B/line
#define ACCS   21                                     // acc stride (coprime w/ 32 banks)
#define SZF    1048576.0f                             // 2^20 scale for z/ex sums
#define SWF    16777216.0f                            // 2^24 scale for w sum

typedef int nat_i2 __attribute__((ext_vector_type(2)));   // builtin-legal int2

// monotone float<->uint order mapping (for LDS atomicMax on floats)
__device__ __forceinline__ unsigned fkey(float f) {
    unsigned b = __float_as_uint(f);
    return (b & 0x80000000u) ? ~b : (b | 0x80000000u);
}
__device__ __forceinline__ float finv(unsigned u) {
    unsigned b = (u & 0x80000000u) ? (u ^ 0x80000000u) : ~u;
    return __uint_as_float(b);
}

// ============ K1: fused node projection (fp16 z) + bucket append ==========
// Round-2 proven kernel, verbatim (best measured standalone: ~70 us).
__global__ __launch_bounds__(1024) void proj_append_kernel(
    const float* __restrict__ h,
    const float* __restrict__ W_fc,
    const float* __restrict__ W_attn,
    const float* __restrict__ e,
    const int*   __restrict__ src,
    const int*   __restrict__ dst,
    __half* __restrict__ zh,
    float* __restrict__ a_src_arr,
    float* __restrict__ a_dst_arr,
    int*   __restrict__ cursor,
    nat_i2* __restrict__ records,
    int cap)
{
    __shared__ int  cnt[NBUCK];
    __shared__ int  pfx[NBUCK];
    __shared__ int  combo[NBUCK];
    __shared__ int2 pay[EBC];                    // 48 KB
    __shared__ unsigned short pbkt[EBC];         // 12 KB
    __shared__ int  wsum[16];

    int tid = threadIdx.x;

    if (blockIdx.x < NPB) {
        // ---------------- node projection ----------------
        int i = blockIdx.x * 1024 + tid;
        if (i >= N_NODES) return;

        float acc[OUT_DIM];
#pragma unroll
        for (int j = 0; j < OUT_DIM; ++j) acc[j] = 0.f;

        const float2* __restrict__ hr = (const float2*)(h + (size_t)i * IN_DIM);
#pragma unroll
        for (int kk = 0; kk < IN_DIM / 2; ++kk) {
            float2 hv = hr[kk];
#pragma unroll
            for (int j = 0; j < OUT_DIM; ++j) {
                acc[j] += hv.x * W_fc[j * IN_DIM + 2 * kk]
                        + hv.y * W_fc[j * IN_DIM + 2 * kk + 1];
            }
        }

        float asrc = 0.f, adst = 0.f;
#pragma unroll
        for (int j = 0; j < OUT_DIM; ++j) {
            asrc += acc[j] * W_attn[j];
            adst += acc[j] * W_attn[OUT_DIM + j];
        }

        union { __half hx[16]; uint4 q[2]; } u;
#pragma unroll
        for (int j = 0; j < OUT_DIM; ++j) u.hx[j] = __float2half(acc[j]);
        uint4* __restrict__ zrow = (uint4*)(zh + (size_t)i * OUT_DIM);
        zrow[0] = u.q[0];
        zrow[1] = u.q[1];

        a_src_arr[i] = asrc;
        a_dst_arr[i] = adst;
        return;
    }

    // ---------------- edge append ----------------
    int be = blockIdx.x - NPB;
    long ebase = (long)be * EBC;
    int chunk_n = (int)min((long)EBC, (long)N_EDGES - ebase);

    int dv[EPT], sv[EPT];
    float2 ev[EPT];
#pragma unroll
    for (int j = 0; j < EPT; ++j) {
        int p = tid + j * 1024;
        dv[j] = -1;
        if (p < chunk_n) {
            long eid = ebase + p;
            dv[j] = dst[eid];
            sv[j] = src[eid];
            ev[j] = ((const float2*)e)[eid];
        }
    }

    for (int t = tid; t < NBUCK; t += 1024) cnt[t] = 0;
    __syncthreads();

#pragma unroll
    for (int j = 0; j < EPT; ++j)
        if (dv[j] >= 0) atomicAdd(&cnt[dv[j] >> 6], 1);
    __syncthreads();

    int b0 = 2 * tid, b1 = b0 + 1;
    int c0 = (b0 < NBUCK) ? cnt[b0] : 0;
    int c1 = (b1 < NBUCK) ? cnt[b1] : 0;
    if (b0 < NBUCK) cnt[b0] = 0;
    if (b1 < NBUCK) cnt[b1] = 0;
    int gb0 = 0, gb1 = 0;
    if (c0) gb0 = atomicAdd(&cursor[b0 * CSTR], c0);   // in flight across scan
    if (c1) gb1 = atomicAdd(&cursor[b1 * CSTR], c1);

    int ts = c0 + c1;
    {
        int lane = tid & 63, wid = tid >> 6;
        int x = ts;
#pragma unroll
        for (int off = 1; off < 64; off <<= 1) {
            int y = __shfl_up(x, off, 64);
            if (lane >= off) x += y;
        }
        if (lane == 63) wsum[wid] = x;
        __syncthreads();
        if (wid == 0) {
            int v = (lane < 16) ? wsum[lane] : 0;
#pragma unroll
            for (int off = 1; off < 16; off <<= 1) {
                int y = __shfl_up(v, off, 64);
                if (lane >= off) v += y;
            }
            if (lane < 16) wsum[lane] = v;
        }
        __syncthreads();
        int texcl = x - ts + (wid ? wsum[wid - 1] : 0);
        if (b0 < NBUCK) { pfx[b0] = texcl;      combo[b0] = b0 * cap + gb0 - texcl; }
        if (b1 < NBUCK) { pfx[b1] = texcl + c0; combo[b1] = b1 * cap + gb1 - (texcl + c0); }
    }
    __syncthreads();

#pragma unroll
    for (int j = 0; j < EPT; ++j) {
        if (dv[j] >= 0) {
            int b = dv[j] >> 6;
            union { __half2 h2; int i; } uu;
            uu.h2.x = __float2half(ev[j].x);
            uu.h2.y = __float2half(ev[j].y);
            int r = atomicAdd(&cnt[b], 1);
            int q = pfx[b] + r;
            pay[q]  = make_int2(uu.i, sv[j] | ((dv[j] & 63) << 17));
            pbkt[q] = (unsigned short)b;
        }
    }
    __syncthreads();

    for (int p = tid; p < chunk_n; p += 1024) {
        int2 v = pay[p];
        int bb = pbkt[p];
        int pos = combo[bb] + p;
        if (pos < (bb + 1) * cap) {                  // overflow: >40 sigma
            nat_i2 vv; vv.x = v.x; vv.y = v.y;
            __builtin_nontemporal_store(vv, records + pos);
        }
    }
}

// ============ K2: edge-parallel gather, fixed-point LDS int atomics =======
// Pass A: per-node max of logit via LDS atomicMax (uint-mapped float) ==
// reference's segment_max, so w' = exp(ea-m) in (0,1] -> fixed point safe.
// Pass B: each LANE owns an edge; 19 no-return ds_add_u32 into acc[node][21].
// No hist, no scan, no inverse permutation, no serial per-node loop.
// Overflow: deg<=~80, |z|<~10 -> |sum| < 800*2^20 < 2^31; w-sum < 80*2^24.
// Quantization ~3e-5 << fp16-z error (passing at absmax 0.03125).
__global__ __launch_bounds__(1024) void gather_fx_kernel(
    const int*    __restrict__ cursor,
    const nat_i2* __restrict__ records,
    const __half* __restrict__ zh,
    const float*  __restrict__ a_src_arr,
    const float*  __restrict__ a_dst_arr,
    const float*  __restrict__ W_attn,
    const float*  __restrict__ W_edge,
    const float*  __restrict__ W_e2n,
    float* __restrict__ out, int cap)
{
    __shared__ unsigned maxv[64];                // per-node logit max (mapped)
    __shared__ int      acci[64 * ACCS];         // 5.25 KB fixed-point sums
    __shared__ float    adst_l[64];
    __shared__ float    we2n_s[2 * OUT_DIM];

    int b   = blockIdx.x;
    int tid = threadIdx.x;
    long lo = (long)b * cap;
    int n   = cursor[b * CSTR];
    int nl  = n < cap ? n : cap;

    if (tid < 64) {
        maxv[tid] = 0u;                          // decodes below any real key
        int node = (b << 6) + tid;
        adst_l[tid] = (node < N_NODES) ? a_dst_arr[node] : 0.f;
    }
    if (tid < 2 * OUT_DIM) we2n_s[tid] = W_e2n[tid];
    for (int t = tid; t < 64 * ACCS; t += 1024) acci[t] = 0;
    __syncthreads();

    float we00 = W_edge[0], we01 = W_edge[1], we10 = W_edge[2], we11 = W_edge[3];
    float wa0  = W_attn[2 * OUT_DIM], wa1 = W_attn[2 * OUT_DIM + 1];

    // ---- pass A: per-node max (regular loads keep records L2-hot for B) ----
    for (int k = tid; k < nl; k += 1024) {
        nat_i2 r = records[lo + k];
        int s  = r.y & 0x1FFFF;
        int ld = (r.y >> 17) & 63;
        union { int i; __half2 h2; } ue; ue.i = r.x;
        float e0 = __low2float(ue.h2), e1 = __high2float(ue.h2);
        float ex0 = e0 * we00 + e1 * we01;
        float ex1 = e0 * we10 + e1 * we11;
        float a  = a_src_arr[s] + adst_l[ld] + ex0 * wa0 + ex1 * wa1;
        float ea = (a > 0.f) ? a : 0.01f * a;
        atomicMax(&maxv[ld], fkey(ea));
    }
    __syncthreads();

    // ---- pass B: edge-parallel fixed-point accumulation ----
    for (int k = tid; k < nl; k += 1024) {
        nat_i2 r = records[lo + k];              // L2-hit (just streamed)
        int s  = r.y & 0x1FFFF;
        int ld = (r.y >> 17) & 63;
        union { int i; __half2 h2; } ue; ue.i = r.x;
        float e0 = __low2float(ue.h2), e1 = __high2float(ue.h2);
        float ex0 = e0 * we00 + e1 * we01;
        float ex1 = e0 * we10 + e1 * we11;
        float a  = a_src_arr[s] + adst_l[ld] + ex0 * wa0 + ex1 * wa1;
        float ea = (a > 0.f) ? a : 0.01f * a;    // identical recompute to pass A
        float m  = finv(maxv[ld]);
        float w  = __expf(ea - m);               // in (0,1]

        const uint4* __restrict__ zr = (const uint4*)(zh + (size_t)s * OUT_DIM);
        uint4 z0 = zr[0], z1 = zr[1];

        int* ab = acci + ld * ACCS;
        union { unsigned u; __half2 h2; } t2;
        float ws = w * SZF;
        t2.u = z0.x; atomicAdd(ab + 0,  __float2int_rn(ws * __low2float(t2.h2)));
                     atomicAdd(ab + 1,  __float2int_rn(ws * __high2float(t2.h2)));
        t2.u = z0.y; atomicAdd(ab + 2,  __float2int_rn(ws * __low2float(t2.h2)));
                     atomicAdd(ab + 3,  __float2int_rn(ws * __high2float(t2.h2)));
        t2.u = z0.z; atomicAdd(ab + 4,  __float2int_rn(ws * __low2float(t2.h2)));
                     atomicAdd(ab + 5,  __float2int_rn(ws * __high2float(t2.h2)));
        t2.u = z0.w; atomicAdd(ab + 6,  __float2int_rn(ws * __low2float(t2.h2)));
                     atomicAdd(ab + 7,  __float2int_rn(ws * __high2float(t2.h2)));
        t2.u = z1.x; atomicAdd(ab + 8,  __float2int_rn(ws * __low2float(t2.h2)));
                     atomicAdd(ab + 9,  __float2int_rn(ws * __high2float(t2.h2)));
        t2.u = z1.y; atomicAdd(ab + 10, __float2int_rn(ws * __low2float(t2.h2)));
                     atomicAdd(ab + 11, __float2int_rn(ws * __high2float(t2.h2)));
        t2.u = z1.z; atomicAdd(ab + 12, __float2int_rn(ws * __low2float(t2.h2)));
                     atomicAdd(ab + 13, __float2int_rn(ws * __high2float(t2.h2)));
        t2.u = z1.w; atomicAdd(ab + 14, __float2int_rn(ws * __low2float(t2.h2)));
                     atomicAdd(ab + 15, __float2int_rn(ws * __high2float(t2.h2)));
        atomicAdd(ab + 16, __float2int_rn(w * SWF));
        atomicAdd(ab + 17, __float2int_rn(ws * ex0));
        atomicAdd(ab + 18, __float2int_rn(ws * ex1));
    }
    __syncthreads();

    // ---- epilogue: 64 nodes x 16 features == exactly 1024 threads ----
    int ln   = tid >> 4;
    int j    = tid & 15;
    int node = (b << 6) + ln;
    if (node < N_NODES) {
        const int* ab = acci + ln * ACCS;
        int swi = ab[16];                        // >= 2^24 if any edge
        float num  = (float)ab[j]  * (1.f / SZF);
        float ex0s = (float)ab[17] * (1.f / SZF);
        float ex1s = (float)ab[18] * (1.f / SZF);
        float ez   = ex0s * we2n_s[2 * j] + ex1s * we2n_s[2 * j + 1];
        float iv   = (swi != 0) ? (SWF / (float)swi) : 0.f;
        out[(size_t)node * OUT_DIM + j] = (num + ez) * iv;
    }
}

// ================= last-resort atomic path (round-1, known-passing) =======

__global__ __launch_bounds__(256) void node_proj_fb_kernel(
    const float* __restrict__ h,
    const float* __restrict__ W_fc,
    const float* __restrict__ W_attn,
    float* __restrict__ z,
    float* __restrict__ a_src_arr,
    float* __restrict__ a_dst_arr,
    float* __restrict__ denom,
    float* __restrict__ out)
{
    int i = blockIdx.x * blockDim.x + threadIdx.x;
    if (i >= N_NODES) return;

    float acc[OUT_DIM];
#pragma unroll
    for (int j = 0; j < OUT_DIM; ++j) acc[j] = 0.f;

    const float2* __restrict__ hr = (const float2*)(h + (size_t)i * IN_DIM);
#pragma unroll
    for (int kk = 0; kk < IN_DIM / 2; ++kk) {
        float2 hv = hr[kk];
#pragma unroll
        for (int j = 0; j < OUT_DIM; ++j) {
            acc[j] += hv.x * W_fc[j * IN_DIM + 2 * kk]
                    + hv.y * W_fc[j * IN_DIM + 2 * kk + 1];
        }
    }

    float asrc = 0.f, adst = 0.f;
#pragma unroll
    for (int j = 0; j < OUT_DIM; ++j) {
        asrc += acc[j] * W_attn[j];
        adst += acc[j] * W_attn[OUT_DIM + j];
    }

    float4* __restrict__ zrow = (float4*)(z + (size_t)i * OUT_DIM);
    zrow[0] = make_float4(acc[0],  acc[1],  acc[2],  acc[3]);
    zrow[1] = make_float4(acc[4],  acc[5],  acc[6],  acc[7]);
    zrow[2] = make_float4(acc[8],  acc[9],  acc[10], acc[11]);
    zrow[3] = make_float4(acc[12], acc[13], acc[14], acc[15]);

    a_src_arr[i] = asrc;
    a_dst_arr[i] = adst;
    denom[i] = 0.f;

    float4 z4 = make_float4(0.f, 0.f, 0.f, 0.f);
    float4* __restrict__ orow = (float4*)(out + (size_t)i * OUT_DIM);
    orow[0] = z4; orow[1] = z4; orow[2] = z4; orow[3] = z4;
}

__global__ __launch_bounds__(256) void edge_kernel(
    const float* __restrict__ e,
    const int*   __restrict__ src,
    const int*   __restrict__ dst,
    const float* __restrict__ W_attn,
    const float* __restrict__ W_edge,
    const float* __restrict__ W_e2n,
    const float* __restrict__ z,
    const float* __restrict__ a_src_arr,
    const float* __restrict__ a_dst_arr,
    float* __restrict__ denom,
    float* __restrict__ out)
{
    int eid = blockIdx.x * blockDim.x + threadIdx.x;
    if (eid >= N_EDGES) return;

    int s = src[eid];
    int d = dst[eid];

    float2 ev = ((const float2*)e)[eid];
    float ex0 = ev.x * W_edge[0] + ev.y * W_edge[1];
    float ex1 = ev.x * W_edge[2] + ev.y * W_edge[3];

    float a = a_src_arr[s] + a_dst_arr[d]
            + ex0 * W_attn[2 * OUT_DIM] + ex1 * W_attn[2 * OUT_DIM + 1];
    float ea = (a > 0.f) ? a : 0.01f * a;
    float w  = __expf(ea);

    unsafeAtomicAdd(denom + d, w);

    const float4* __restrict__ zrow = (const float4*)(z + (size_t)s * OUT_DIM);
    float4 z0 = zrow[0], z1 = zrow[1], z2 = zrow[2], z3 = zrow[3];

    float* __restrict__ orow = out + (size_t)d * OUT_DIM;
    float zs[OUT_DIM] = { z0.x, z0.y, z0.z, z0.w,
                          z1.x, z1.y, z1.z, z1.w,
                          z2.x, z2.y, z2.z, z2.w,
                          z3.x, z3.y, z3.z, z3.w };
#pragma unroll
    for (int j = 0; j < OUT_DIM; ++j) {
        float ez = ex0 * W_e2n[2 * j] + ex1 * W_e2n[2 * j + 1];
        unsafeAtomicAdd(orow + j, w * (zs[j] + ez));
    }
}

__global__ __launch_bounds__(256) void normalize_kernel(
    float* __restrict__ out, const float* __restrict__ denom)
{
    int tid = blockIdx.x * blockDim.x + threadIdx.x;
    const int total = N_NODES * OUT_DIM / 4;
    if (tid >= total) return;
    int n = tid >> 2;
    float dn = denom[n];
    float inv = (dn != 0.f) ? (1.f / dn) : 0.f;
    float4 v = ((float4*)out)[tid];
    v.x *= inv; v.y *= inv; v.z *= inv; v.w *= inv;
    ((float4*)out)[tid] = v;
}

extern "C" void kernel_launch(void* const* d_in, const int* in_sizes, int n_in,
                              void* d_out, int out_size, void* d_ws, size_t ws_size,
                              hipStream_t stream)
{
    const float* h      = (const float*)d_in[0];
    const float* e      = (const float*)d_in[1];
    const int*   src    = (const int*)  d_in[2];
    const int*   dst    = (const int*)  d_in[3];
    const float* W_fc   = (const float*)d_in[4];
    const float* W_attn = (const float*)d_in[5];
    const float* W_edge = (const float*)d_in[6];
    const float* W_e2n  = (const float*)d_in[7];
    float* out = (float*)d_out;

    char* ws = (char*)d_ws;

    // ---- layout: zh | a_src | a_dst | padded cursor | records ----
    size_t off = 0;
    __half* zh        = (__half*)(ws + off); off += (size_t)N_NODES * OUT_DIM * 2;
    float*  a_src_arr = (float*) (ws + off); off += (size_t)N_NODES * 4;
    float*  a_dst_arr = (float*) (ws + off); off += (size_t)N_NODES * 4;
    off = (off + 255) & ~(size_t)255;
    int*    cursor = (int*)(ws + off);
    size_t  cur_bytes = (size_t)NBUCK * CSTR * 4;
    off += (cur_bytes + 255) & ~(size_t)255;
    size_t rec_off = (off + 255) & ~(size_t)255;

    // per-bucket capacity tiers: mean load 2048, sigma ~45
    int cap = 0;
    if      (ws_size >= rec_off + (size_t)NBUCK * 4096 * 8) cap = 4096;
    else if (ws_size >= rec_off + (size_t)NBUCK * 3072 * 8) cap = 3072;
    else if (ws_size >= rec_off + (size_t)NBUCK * 2560 * 8) cap = 2560;
    else if (ws_size >= rec_off + (size_t)NBUCK * 2304 * 8) cap = 2304;

    if (cap) {
        nat_i2* records = (nat_i2*)(ws + rec_off);

        hipMemsetAsync(cursor, 0, cur_bytes, stream);

        proj_append_kernel<<<NPB + NEB, 1024, 0, stream>>>(
            h, W_fc, W_attn, e, src, dst,
            zh, a_src_arr, a_dst_arr, cursor, records, cap);

        gather_fx_kernel<<<NBUCK, 1024, 0, stream>>>(
            cursor, records, zh, a_src_arr, a_dst_arr,
            W_attn, W_edge, W_e2n, out, cap);
    } else {
        // -------- round-1 atomic fallback (needs ~8 MB) --------
        size_t foff = 0;
        float* z     = (float*)(ws + foff); foff += (size_t)N_NODES * OUT_DIM * 4;
        float* asrc  = (float*)(ws + foff); foff += (size_t)N_NODES * 4;
        float* adst  = (float*)(ws + foff); foff += (size_t)N_NODES * 4;
        float* denom = (float*)(ws + foff); foff += (size_t)N_NODES * 4;

        node_proj_fb_kernel<<<(N_NODES + 255) / 256, 256, 0, stream>>>(
            h, W_fc, W_attn, z, asrc, adst, denom, out);

        edge_kernel<<<(N_EDGES + 255) / 256, 256, 0, stream>>>(
            e, src, dst, W_attn, W_edge, W_e2n, z, asrc, adst, denom, out);

        normalize_kernel<<<(N_NODES * OUT_DIM / 4 + 255) / 256, 256, 0, stream>>>(
            out, denom);
    }
}